// Round 1
// baseline (2995.224 us; speedup 1.0000x reference)
//
#include <hip/hip_runtime.h>
#include <math.h>

#define B_ 8
#define N_ 4096
#define K_ 20
#define BN_ (B_*N_)

// ---------------------------------------------------------------- utilities
__global__ void zero_kernel(float* p, int n)
{
    for (int e = threadIdx.x; e < n; e += 256) p[e] = 0.f;
}

// mean/rstd from accumulated sum/sumsq.  layout: [sum(H), sumsq(H), mean(H), rstd(H)]
__global__ void finalize_kernel(float* st, int H, float invCount)
{
    int t = threadIdx.x;
    if (t < H) {
        float mean = st[t] * invCount;
        float var  = fmaxf(st[H + t] * invCount - mean * mean, 0.f);
        st[2*H + t] = mean;
        st[3*H + t] = 1.f / sqrtf(var + 1e-5f);
    }
}

// ---------------------------------------------------------------- kNN, C=4
// block 1024 (16 waves), one query row per wave; full batch (64KB) in LDS.
// Per lane: 64 candidate dists in registers; selection = cached top-2 + wave argmin.
__global__ __launch_bounds__(1024) void knn4_kernel(const float* __restrict__ x, int* __restrict__ idxout)
{
    __shared__ float4 xt[N_];
    const int b = blockIdx.y;
    const int t = threadIdx.x;
    const float4* xg = (const float4*)x + b*N_;
    for (int e = t; e < N_; e += 1024) xt[e] = xg[e];
    __syncthreads();
    const int w = t >> 6, L = t & 63;
    const int n = blockIdx.x*16 + w;
    const float4 q = xt[n];
    float d[64];
    #pragma unroll
    for (int s = 0; s < 64; ++s) {
        float4 v = xt[(s<<6) | L];
        float nn = v.x*v.x + v.y*v.y + v.z*v.z + v.w*v.w;
        float dp = q.x*v.x + q.y*v.y + q.z*v.z + q.w*v.w;
        d[s] = nn - 2.f*dp;   // |xn|^2 dropped: rank-equivalent
    }
    const float MX = 3.4e38f;
    float m1 = MX, m2 = MX; int i1 = 0, i2 = 0;
    #pragma unroll
    for (int j = 0; j < 64; ++j) {
        float v = d[j];
        bool c1 = v < m1, c2 = v < m2;
        m2 = c1 ? m1 : (c2 ? v : m2);
        i2 = c1 ? i1 : (c2 ? j : i2);
        m1 = c1 ? v : m1;
        i1 = c1 ? j : i1;
    }
    bool have2 = true;
    unsigned long long used = 0;
    int mywin = 0;
    for (int r = 0; r < K_; ++r) {
        float bv = m1; int bg = (i1<<6) | L;     // bg == candidate point index
        #pragma unroll
        for (int off = 32; off; off >>= 1) {
            float ov = __shfl_xor(bv, off);
            int   og = __shfl_xor(bg, off);
            bool tk = (ov < bv) || (ov == bv && og < bg);
            bv = tk ? ov : bv; bg = tk ? og : bg;
        }
        if (L == r) mywin = bg;
        if (L == (bg & 63)) {
            used |= 1ull << i1;
            if (have2) { m1 = m2; i1 = i2; have2 = false; }
            else {
                m1 = MX; m2 = MX; i1 = 0; i2 = 0;
                #pragma unroll
                for (int j = 0; j < 64; ++j) {
                    float v = ((used >> j) & 1ull) ? MX : d[j];
                    bool c1 = v < m1, c2 = v < m2;
                    m2 = c1 ? m1 : (c2 ? v : m2);
                    i2 = c1 ? i1 : (c2 ? j : i2);
                    m1 = c1 ? v : m1;
                    i1 = c1 ? j : i1;
                }
                have2 = true;
            }
        }
    }
    if (L < K_) idxout[(b*N_ + n)*K_ + L] = mywin;
}

// ---------------------------------------------------------------- kNN, C=64
// block 256 (4 waves), one query row per wave.  Candidates tiled through LDS
// (64 rows x 64ch, stride-17 float4 to break bank conflicts).  Dist rows live in
// LDS (2048 per wave); two halves of 2048 candidates, top-20 per half, merge 40->20.
__global__ __launch_bounds__(256) void knn64_kernel(const float* __restrict__ x, const float* __restrict__ nrm,
                                                    int* __restrict__ idxout)
{
    __shared__ float  dist[4*2048];
    __shared__ float4 tile[64*17];
    __shared__ float4 qrow[4*17];
    __shared__ float  tnorm[64];
    const int b = blockIdx.y, t = threadIdx.x;
    const int w = t >> 6, L = t & 63;
    const int n = blockIdx.x*4 + w;
    const float4* xg = (const float4*)x + (size_t)b*N_*16;
    if (L < 16) qrow[w*17 + L] = xg[n*16 + L];
    float* dw = dist + w*2048;
    const float MX = 3.4e38f;
    float va = MX, vb = MX; int ga = 0, gb = 0;
    for (int half = 0; half < 2; ++half) {
        const int cbase = half*2048;
        for (int tt = 0; tt < 32; ++tt) {
            __syncthreads();
            #pragma unroll
            for (int i = 0; i < 4; ++i) {
                int e = t + 256*i;
                int rr = e >> 4, cq = e & 15;
                tile[rr*17 + cq] = xg[(cbase + tt*64 + rr)*16 + cq];
            }
            if (t < 64) tnorm[t] = nrm[b*N_ + cbase + tt*64 + t];
            __syncthreads();
            float dot = 0.f;
            #pragma unroll
            for (int ci = 0; ci < 16; ++ci) {
                float4 qv = qrow[w*17 + ci];
                float4 av = tile[L*17 + ci];
                dot += qv.x*av.x + qv.y*av.y + qv.z*av.z + qv.w*av.w;
            }
            dw[(tt<<6) | L] = tnorm[L] - 2.f*dot;
        }
        // top-20 of this half (32 slots/lane)
        float m1 = MX, m2 = MX; int i1 = 0, i2 = 0;
        for (int j = 0; j < 32; ++j) {
            float v = dw[(j<<6) | L];
            bool c1 = v < m1, c2 = v < m2;
            m2 = c1 ? m1 : (c2 ? v : m2);
            i2 = c1 ? i1 : (c2 ? j : i2);
            m1 = c1 ? v : m1;
            i1 = c1 ? j : i1;
        }
        bool have2 = true;
        unsigned long long used = 0;
        for (int r = 0; r < K_; ++r) {
            float bv = m1; int bg = (i1<<6) | L;
            #pragma unroll
            for (int off = 32; off; off >>= 1) {
                float ov = __shfl_xor(bv, off);
                int   og = __shfl_xor(bg, off);
                bool tk = (ov < bv) || (ov == bv && og < bg);
                bv = tk ? ov : bv; bg = tk ? og : bg;
            }
            if (L == r) { if (half == 0) { va = bv; ga = cbase + bg; } else { vb = bv; gb = cbase + bg; } }
            if (L == (bg & 63)) {
                used |= 1ull << i1;
                if (have2) { m1 = m2; i1 = i2; have2 = false; }
                else {
                    m1 = MX; m2 = MX; i1 = 0; i2 = 0;
                    for (int j = 0; j < 32; ++j) {
                        float v = ((used >> j) & 1ull) ? MX : dw[(j<<6) | L];
                        bool c1 = v < m1, c2 = v < m2;
                        m2 = c1 ? m1 : (c2 ? v : m2);
                        i2 = c1 ? i1 : (c2 ? j : i2);
                        m1 = c1 ? v : m1;
                        i1 = c1 ? j : i1;
                    }
                    have2 = true;
                }
            }
        }
    }
    // merge the two per-half top-20 lists (lanes 0..19 hold 2 items each)
    {
        float e0 = (L < K_) ? va : MX, e1 = (L < K_) ? vb : MX;
        bool cf = e1 < e0;
        float m1 = cf ? e1 : e0, m2 = cf ? e0 : e1;
        int   i1 = cf ? 1 : 0,  i2 = cf ? 0 : 1;
        bool have2 = true;
        int myfin = 0;
        for (int r = 0; r < K_; ++r) {
            float bv = m1; int bg = (i1<<6) | L;
            #pragma unroll
            for (int off = 32; off; off >>= 1) {
                float ov = __shfl_xor(bv, off);
                int   og = __shfl_xor(bg, off);
                bool tk = (ov < bv) || (ov == bv && og < bg);
                bv = tk ? ov : bv; bg = tk ? og : bg;
            }
            int bl = bg & 63, slot = bg >> 6;
            int gan = __shfl(ga, bl), gbn = __shfl(gb, bl);
            if (L == r) myfin = slot ? gbn : gan;
            if (L == bl) {
                if (have2) { m1 = m2; i1 = i2; have2 = false; }
                else { m1 = MX; i1 = 0; }
            }
        }
        if (L < K_) idxout[(b*N_ + n)*K_ + L] = myfin;
    }
}

// ---------------------------------------------------------------- squared norms (C=64)
__global__ __launch_bounds__(256) void sqnorm64_kernel(const float* __restrict__ x, float* __restrict__ nrm)
{
    int p = blockIdx.x*256 + threadIdx.x;
    const float4* x4 = (const float4*)x + p*16;
    float s = 0.f;
    #pragma unroll
    for (int i = 0; i < 16; ++i) {
        float4 v = x4[i];
        s += v.x*v.x + v.y*v.y + v.z*v.z + v.w*v.w;
    }
    nrm[p] = s;
}

// ---------------------------------------------------------------- P/Q precompute
// layer1 decomposition: z1[n,j,:] = P[n] + Q[idx[n,j]],  P = x@(Wt-Wb)+b1, Q = x@Wb
__global__ __launch_bounds__(256) void pq1_kernel(const float* __restrict__ x, const float* __restrict__ W,
                                                  const float* __restrict__ b1,
                                                  float* __restrict__ P, float* __restrict__ Q)
{
    __shared__ float wd[256], wb[256];
    const int t = threadIdx.x;
    wd[t] = W[t] - W[256 + t];
    wb[t] = W[256 + t];
    __syncthreads();
    const int p = blockIdx.x*4 + (t >> 6), c = t & 63;
    const float4 xv = ((const float4*)x)[p];
    float Pv = b1[c] + xv.x*wd[c] + xv.y*wd[64+c] + xv.z*wd[128+c] + xv.w*wd[192+c];
    float Qv =         xv.x*wb[c] + xv.y*wb[64+c] + xv.z*wb[128+c] + xv.w*wb[192+c];
    P[p*64 + c] = Pv;
    Q[p*64 + c] = Qv;
}

__global__ __launch_bounds__(256) void pq2_kernel(const float* __restrict__ x1, const float* __restrict__ W,
                                                  const float* __restrict__ b1,
                                                  float* __restrict__ P, float* __restrict__ Q)
{
    __shared__ float wd[64*128], wb[64*128];
    const int t = threadIdx.x;
    for (int e = t; e < 8192; e += 256) {
        float wt = W[e], wbo = W[8192 + e];
        wd[e] = wt - wbo; wb[e] = wbo;
    }
    __syncthreads();
    const int pl = t >> 7, c = t & 127;
    const float b1v = b1[c];
    for (int p0 = blockIdx.x*2; p0 < BN_; p0 += gridDim.x*2) {
        const int p = p0 + pl;
        float Pv = b1v, Qv = 0.f;
        const float* xrow = x1 + p*64;
        #pragma unroll 8
        for (int k = 0; k < 64; ++k) {
            float xv = xrow[k];
            Pv += xv * wd[k*128 + c];
            Qv += xv * wb[k*128 + c];
        }
        P[p*128 + c] = Pv;
        Q[p*128 + c] = Qv;
    }
}

// ---------------------------------------------------------------- layer-1 BN stats
template<int HO>
__global__ __launch_bounds__(256) void stats_l1_kernel(const float* __restrict__ P, const float* __restrict__ Q,
                                                       const int* __restrict__ idx, float* __restrict__ stOut)
{
    constexpr int G = 256/HO;
    __shared__ float red[256], red2[256];
    const int t = threadIdx.x, c = t % HO, g = t / HO;
    float s = 0.f, s2 = 0.f;
    for (int p = blockIdx.x; p < BN_; p += gridDim.x) {
        const float Pv = P[p*HO + c];
        const int bbase = p & ~(N_-1);
        for (int j = g; j < K_; j += G) {
            int m = idx[p*K_ + j];
            float z = Pv + Q[(bbase + m)*HO + c];
            s += z; s2 += z*z;
        }
    }
    red[t] = s; red2[t] = s2;
    __syncthreads();
    if (t < HO) {
        float a = red[t], a2 = red2[t];
        #pragma unroll
        for (int q = 1; q < G; ++q) { a += red[q*HO + t]; a2 += red2[q*HO + t]; }
        atomicAdd(&stOut[t], a);
        atomicAdd(&stOut[HO + t], a2);
    }
}

// ---------------------------------------------------------------- EdgeConv layer-2
// Per point: h1 = relu(BN1(P+Q[idx])) into LDS, z2 = h1@W2+b2; track per-channel
// max & min over k (for monotone-commute) and accumulate BN2 sum/sumsq.
// blockIdx.y splits the 128 output channels into 64-wide halves (LDS < 64KB).
template<int HO>
__global__ __launch_bounds__(256) void conv_l2_kernel(
    const float* __restrict__ P, const float* __restrict__ Q, const int* __restrict__ idx,
    const float* __restrict__ st1, const float* __restrict__ g1, const float* __restrict__ be1,
    const float* __restrict__ w2, const float* __restrict__ b2,
    float* __restrict__ zmax, float* __restrict__ zmin, float* __restrict__ stOut)
{
    __shared__ float w2s[HO*64];
    __shared__ float h1s[K_*HO];
    __shared__ float redA[256], redB[256];
    const int t = threadIdx.x;
    const int cy = blockIdx.y;
    for (int e = t; e < HO*64; e += 256) {
        int c = e >> 6, cl = e & 63;
        w2s[e] = w2[c*HO + cy*64 + cl];
    }
    const int cA = t % HO;
    const float ac = st1[3*HO + cA] * g1[cA];
    const float bc = be1[cA] - st1[2*HO + cA] * ac;
    const int c2l = t & 63, jh = t >> 6;   // 4 j-groups x 5 j's
    const float b2v = b2[cy*64 + c2l];
    float ssum = 0.f, ssq = 0.f;
    for (int p = blockIdx.x; p < BN_; p += gridDim.x) {
        __syncthreads();
        const int bbase = p & ~(N_-1);
        const float Pv = P[p*HO + cA];
        for (int e = t; e < K_*HO; e += 256) {
            int j = e / HO;
            int m = idx[p*K_ + j];
            float z = Pv + Q[(bbase + m)*HO + cA];
            h1s[e] = fmaxf(z*ac + bc, 0.f);
        }
        __syncthreads();
        float acc[5];
        #pragma unroll
        for (int q = 0; q < 5; ++q) acc[q] = b2v;
        for (int c = 0; c < HO; ++c) {
            float wv = w2s[c*64 + c2l];
            #pragma unroll
            for (int q = 0; q < 5; ++q)
                acc[q] += h1s[(jh + q*4)*HO + c] * wv;
        }
        float mx = acc[0], mn = acc[0];
        #pragma unroll
        for (int q = 0; q < 5; ++q) {
            mx = fmaxf(mx, acc[q]); mn = fminf(mn, acc[q]);
            ssum += acc[q]; ssq += acc[q]*acc[q];
        }
        redA[t] = mx; redB[t] = mn;
        __syncthreads();
        if (t < 64) {
            float M = redA[t], Mn = redB[t];
            #pragma unroll
            for (int g = 1; g < 4; ++g) { M = fmaxf(M, redA[g*64 + t]); Mn = fminf(Mn, redB[g*64 + t]); }
            zmax[p*HO + cy*64 + t] = M;
            zmin[p*HO + cy*64 + t] = Mn;
        }
    }
    __syncthreads();
    redA[t] = ssum; redB[t] = ssq;
    __syncthreads();
    if (t < 64) {
        float s = redA[t], s2 = redB[t];
        #pragma unroll
        for (int g = 1; g < 4; ++g) { s += redA[g*64 + t]; s2 += redB[g*64 + t]; }
        atomicAdd(&stOut[cy*64 + t], s);
        atomicAdd(&stOut[HO + cy*64 + t], s2);
    }
}

// max_j relu(BN(z)) = relu(BN(max_j z)) for gamma>=0, min for gamma<0
template<int HO>
__global__ __launch_bounds__(256) void conv_fin_kernel(
    const float* __restrict__ zmax, const float* __restrict__ zmin,
    const float* __restrict__ st2, const float* __restrict__ g2, const float* __restrict__ be2,
    float* __restrict__ out)
{
    int e = blockIdx.x*256 + threadIdx.x;
    int c = e & (HO-1);
    float g = g2[c];
    float a = st2[3*HO + c] * g;
    float sel = (g >= 0.f) ? zmax[e] : zmin[e];
    out[e] = fmaxf((sel - st2[2*HO + c]) * a + be2[c], 0.f);
}

// ---------------------------------------------------------------- classifier
__global__ __launch_bounds__(256) void cls1_kernel(
    const float* __restrict__ x1, const float* __restrict__ x2f,
    const float* __restrict__ W, const float* __restrict__ b1,
    float* __restrict__ z, float* __restrict__ stOut)
{
    __shared__ float ws[192*64];
    __shared__ float xr[4*192];
    __shared__ float red[256], red2[256];
    const int t = threadIdx.x, cy = blockIdx.y;
    for (int e = t; e < 192*64; e += 256) {
        int c = e >> 6, cl = e & 63;
        ws[e] = W[c*128 + cy*64 + cl];
    }
    const int pl = t >> 6, c2l = t & 63;
    const float b1v = b1[cy*64 + c2l];
    float ssum = 0.f, ssq = 0.f;
    for (int p0 = blockIdx.x*4; p0 < BN_; p0 += gridDim.x*4) {
        __syncthreads();
        for (int l = t; l < 4*192; l += 256) {
            int pp = l / 192, cc = l % 192;
            xr[l] = (cc < 64) ? x1[(p0+pp)*64 + cc] : x2f[(p0+pp)*128 + cc - 64];
        }
        __syncthreads();
        float acc = b1v;
        const float* xx = xr + pl*192;
        #pragma unroll 8
        for (int c = 0; c < 192; ++c) acc += xx[c] * ws[c*64 + c2l];
        z[(p0+pl)*128 + cy*64 + c2l] = acc;
        ssum += acc; ssq += acc*acc;
    }
    __syncthreads();
    red[t] = ssum; red2[t] = ssq;
    __syncthreads();
    if (t < 64) {
        float s = red[t], s2 = red2[t];
        #pragma unroll
        for (int g = 1; g < 4; ++g) { s += red[g*64 + t]; s2 += red2[g*64 + t]; }
        atomicAdd(&stOut[cy*64 + t], s);
        atomicAdd(&stOut[128 + cy*64 + t], s2);
    }
}

__global__ __launch_bounds__(256) void cls_fin_kernel(
    const float* __restrict__ z, const float* __restrict__ st,
    const float* __restrict__ g, const float* __restrict__ be,
    const float* __restrict__ w2, const float* __restrict__ b2,
    float* __restrict__ out)
{
    const int t = threadIdx.x, w = t >> 6, L = t & 63;
    const int p = blockIdx.x*4 + w;
    float s = 0.f;
    #pragma unroll
    for (int h = 0; h < 2; ++h) {
        int c = L + h*64;
        float v = (z[p*128 + c] - st[256 + c]) * st[384 + c] * g[c] + be[c];
        s += fmaxf(v, 0.f) * w2[c];
    }
    #pragma unroll
    for (int off = 32; off; off >>= 1) s += __shfl_xor(s, off);
    if (L == 0) out[p] = s + b2[0];
}

// ---------------------------------------------------------------- launch
extern "C" void kernel_launch(void* const* d_in, const int* in_sizes, int n_in,
                              void* d_out, int out_size, void* d_ws, size_t ws_size,
                              hipStream_t stream)
{
    const float* x      = (const float*)d_in[0];
    const float* c1_w1  = (const float*)d_in[1];
    const float* c1_b1  = (const float*)d_in[2];
    const float* c1_g1  = (const float*)d_in[3];
    const float* c1_be1 = (const float*)d_in[4];
    const float* c1_w2  = (const float*)d_in[5];
    const float* c1_b2  = (const float*)d_in[6];
    const float* c1_g2  = (const float*)d_in[7];
    const float* c1_be2 = (const float*)d_in[8];
    const float* c2_w1  = (const float*)d_in[9];
    const float* c2_b1  = (const float*)d_in[10];
    const float* c2_g1  = (const float*)d_in[11];
    const float* c2_be1 = (const float*)d_in[12];
    const float* c2_w2  = (const float*)d_in[13];
    const float* c2_b2  = (const float*)d_in[14];
    const float* c2_g2  = (const float*)d_in[15];
    const float* c2_be2 = (const float*)d_in[16];
    const float* cls_w1 = (const float*)d_in[17];
    const float* cls_b1 = (const float*)d_in[18];
    const float* cls_g1 = (const float*)d_in[19];
    const float* cls_be1= (const float*)d_in[20];
    const float* cls_w2 = (const float*)d_in[21];
    const float* cls_b2 = (const float*)d_in[22];
    (void)in_sizes; (void)n_in; (void)out_size; (void)ws_size;

    char* ws = (char*)d_ws;
    size_t off = 0;
    auto alloc = [&](size_t bytes) { char* p = ws + off; off += (bytes + 255) & ~255ull; return p; };
    float* A    = (float*)alloc((size_t)16<<20);   // P1 -> P2 -> zcls
    float* Bq   = (float*)alloc((size_t)16<<20);   // Q1 -> Q2
    float* zmax = (float*)alloc((size_t)16<<20);
    float* zmin = (float*)alloc((size_t)16<<20);
    float* x1b  = (float*)alloc((size_t)8<<20);
    float* x2b  = (float*)alloc((size_t)16<<20);
    int*   idx  = (int*)  alloc((size_t)BN_*K_*4); // idx1 -> idx2
    float* nrm  = (float*)alloc((size_t)BN_*4);
    float* st   = (float*)alloc((size_t)5*512*4);
    float *st0 = st, *st1 = st+512, *st2 = st+1024, *st3 = st+1536, *st4 = st+2048;

    zero_kernel<<<1, 256, 0, stream>>>(st, 5*512);

    // ---- EdgeConv 1
    knn4_kernel<<<dim3(N_/16, B_), 1024, 0, stream>>>(x, idx);
    pq1_kernel<<<BN_/4, 256, 0, stream>>>(x, c1_w1, c1_b1, A, Bq);
    stats_l1_kernel<64><<<2048, 256, 0, stream>>>(A, Bq, idx, st0);
    finalize_kernel<<<1, 128, 0, stream>>>(st0, 64, 1.f/655360.f);
    conv_l2_kernel<64><<<dim3(2048,1), 256, 0, stream>>>(A, Bq, idx, st0, c1_g1, c1_be1, c1_w2, c1_b2, zmax, zmin, st1);
    finalize_kernel<<<1, 128, 0, stream>>>(st1, 64, 1.f/655360.f);
    conv_fin_kernel<64><<<BN_*64/256, 256, 0, stream>>>(zmax, zmin, st1, c1_g2, c1_be2, x1b);

    // ---- EdgeConv 2
    sqnorm64_kernel<<<BN_/256, 256, 0, stream>>>(x1b, nrm);
    knn64_kernel<<<dim3(N_/4, B_), 256, 0, stream>>>(x1b, nrm, idx);
    pq2_kernel<<<1024, 256, 0, stream>>>(x1b, c2_w1, c2_b1, A, Bq);
    stats_l1_kernel<128><<<2048, 256, 0, stream>>>(A, Bq, idx, st2);
    finalize_kernel<<<1, 128, 0, stream>>>(st2, 128, 1.f/655360.f);
    conv_l2_kernel<128><<<dim3(2048,2), 256, 0, stream>>>(A, Bq, idx, st2, c2_g1, c2_be1, c2_w2, c2_b2, zmax, zmin, st3);
    finalize_kernel<<<1, 128, 0, stream>>>(st3, 128, 1.f/655360.f);
    conv_fin_kernel<128><<<BN_*128/256, 256, 0, stream>>>(zmax, zmin, st3, c2_g2, c2_be2, x2b);

    // ---- classifier
    cls1_kernel<<<dim3(512,2), 256, 0, stream>>>(x1b, x2b, cls_w1, cls_b1, A, st4);
    finalize_kernel<<<1, 128, 0, stream>>>(st4, 128, 1.f/32768.f);
    cls_fin_kernel<<<BN_/4, 256, 0, stream>>>(A, st4, cls_g1, cls_be1, cls_w2, cls_b2, (float*)d_out);
}